// Round 1
// baseline (209.808 us; speedup 1.0000x reference)
//
#include <hip/hip_runtime.h>
#include <math.h>

// ---------------------------------------------------------------------------
// CNN_88098369175791: fully-fused single-block implementation.
// Latency-bound problem (~4 MFLOP, sequential dependency chain) -> one kernel,
// one workgroup (1024 threads), LDS arena with time-multiplexed regions.
// ---------------------------------------------------------------------------

#define NT 1024

// dims
constexpr int WLEN = 140;
constexpr int TDN  = 14;
constexpr int NOFC = 119;   // OFC / E1
constexpr int NE2  = 16;

// ---- LDS arena offsets (floats). Regions are reused across phases; comments
// give live ranges.  Total 15534 floats = 62136 B (< 64 KB static limit).
constexpr int EEGQ = 0;      // 16*119      live P0..P3
constexpr int WAVA = 1904;   // 140         live P0..P3
constexpr int WAVB = 2044;   // 140         live P0..P3
constexpr int QP   = 2184;   // 16*119      P1/P2 scratch (td qp, shared A/B)
constexpr int KP   = 4088;   // 14*119
constexpr int VP   = 5754;   // 14*119
constexpr int ATT  = 7420;   // 16*14
constexpr int MMAT = 7644;   // 16*16
constexpr int AV   = 7900;   // 16*119
constexpr int WATT = 9804;   // 16*119      dead before PA/PB written (P3)
// persistent across the 4 cm-MHAs:
constexpr int PA   = 9758;   // 16*119      written P3 (WATT/AV dead by then)
constexpr int PB   = 11662;  // 16*119
constexpr int LNB  = 13566;  // 16*119      -> ends 15470
constexpr int SM   = 15470;  // smalls: vA[16], vB[16], weight[16], mi -> 64
// cm-MHA scratch (P4) reuses [0, 9758):
constexpr int CQ    = 0;     // 119*16
constexpr int CK    = 1904;  // 119*16
constexpr int CV    = 3808;  // 119*16
constexpr int OKEEP = 5712;  // 119*16  (o0 then o2)
constexpr int OCUR  = 7616;  // 119*16  (o1 then o3)
constexpr int DOF   = 9520;  // 238 (d0|d1 -> dd in place)   ends 9758
constexpr int HOF   = 9758;  // 119 (P5; PA dead by then)

constexpr int ARENA = 15534;

struct Args {
  const float *x, *td_in_w, *td_in_b, *td_out_w, *td_out_b;
  const float *cm_in_w, *cm_in_b, *cm_out_w, *cm_out_b;
  const float *mc_w, *mc_b, *max_fc_w, *max_fc_b, *proj_w;
  const float *ln_g, *ln_b, *fc_w, *fc_b;
  const float *out1_w, *out1_b, *out2_w, *out2_b;
  float *out;
};

__device__ __forceinline__ float sigmf(float v) {
  return 1.0f / (1.0f + expf(-v));
}

__global__ __launch_bounds__(NT) void fused_cnn_kernel(Args a) {
  __shared__ float S[ARENA];
  const int tid = threadIdx.x;

  // ---- P0: load wavA, wavB, eeg_q -------------------------------------
  for (int t = tid; t < 16 * NOFC; t += NT) {
    int c = t / NOFC, tt = t - c * NOFC;
    S[EEGQ + t] = a.x[(1 + c) * WLEN + (WLEN - NOFC) + tt];
  }
  for (int t = tid; t < WLEN; t += NT) {
    S[WAVA + t] = a.x[t];
    S[WAVB + t] = a.x[17 * WLEN + t];
  }
  __syncthreads();

  // ---- P1: qp = eeg_q @ Wq^T + bq  (shared by both td-MHAs) -----------
  for (int o = tid; o < 16 * NOFC; o += NT) {
    int i = o / NOFC, e = o - i * NOFC;
    const float *w = a.td_in_w + e * NOFC;
    const float *q = S + EEGQ + i * NOFC;
    float acc = a.td_in_b[e];
    for (int ep = 0; ep < NOFC; ++ep) acc += q[ep] * w[ep];
    S[QP + o] = acc;
  }
  // (sync folded into first sync inside the ab loop)

  // ---- P2: two td-MHAs (A then B), identical weights, different wave --
  for (int ab = 0; ab < 2; ++ab) {
    const int wav = ab ? WAVB : WAVA;

    // kp[j][e], vp[j][e]: dot(wav[j:j+119], td_in_w[row,:]) + b
    for (int o = tid; o < 2 * TDN * NOFC; o += NT) {
      int which = o / (TDN * NOFC);      // 0: kp, 1: vp
      int rem = o - which * (TDN * NOFC);
      int j = rem / NOFC, e = rem - j * NOFC;
      int row = (which ? 2 * NOFC : NOFC) + e;
      const float *w = a.td_in_w + row * NOFC;
      const float *wv = S + wav + j;
      float acc = a.td_in_b[row];
      for (int ep = 0; ep < NOFC; ++ep) acc += wv[ep] * w[ep];
      S[(which ? VP : KP) + j * NOFC + e] = acc;
    }
    __syncthreads();

    // scores (16x14), scale 119^-0.5
    for (int o = tid; o < 16 * TDN; o += NT) {
      int i = o / TDN, j = o - i * TDN;
      const float *qr = S + QP + i * NOFC;
      const float *kr = S + KP + j * NOFC;
      float acc = 0.f;
      for (int e = 0; e < NOFC; ++e) acc += qr[e] * kr[e];
      S[ATT + o] = acc * 0.09166984970282113f;
    }
    __syncthreads();

    // stable softmax per row (16 rows of 14)
    if (tid < 16) {
      float m = -1e30f;
      for (int j = 0; j < TDN; ++j) m = fmaxf(m, S[ATT + tid * TDN + j]);
      float sum = 0.f;
      for (int j = 0; j < TDN; ++j) {
        float p = expf(S[ATT + tid * TDN + j] - m);
        S[ATT + tid * TDN + j] = p;
        sum += p;
      }
      float inv = 1.0f / sum;
      for (int j = 0; j < TDN; ++j) S[ATT + tid * TDN + j] *= inv;
    }
    __syncthreads();

    // av = attn @ vp  (16x119, 14-MAC)
    for (int o = tid; o < 16 * NOFC; o += NT) {
      int i = o / NOFC, e = o - i * NOFC;
      float acc = 0.f;
      for (int j = 0; j < TDN; ++j) acc += S[ATT + i * TDN + j] * S[VP + j * NOFC + e];
      S[AV + o] = acc;
    }
    __syncthreads();

    // watt = av @ out_w^T + out_b   (16x119, 119-MAC)
    for (int o = tid; o < 16 * NOFC; o += NT) {
      int k = o / NOFC, e = o - k * NOFC;
      const float *w = a.td_out_w + e * NOFC;
      const float *av = S + AV + k * NOFC;
      float acc = a.td_out_b[e];
      for (int ep = 0; ep < NOFC; ++ep) acc += av[ep] * w[ep];
      S[WATT + o] = acc;
    }
    __syncthreads();

    // M[i][k] = sum_t eeg_q[i][t] * watt[k][t]
    for (int o = tid; o < 256; o += NT) {
      int i = o >> 4, k = o & 15;
      float acc = 0.f;
      for (int t = 0; t < NOFC; ++t) acc += S[EEGQ + i * NOFC + t] * S[WATT + k * NOFC + t];
      S[MMAT + o] = acc;
    }
    __syncthreads();

    // v[k] = relu(mc_w[ab] . M[:,k] + mc_b[ab])
    if (tid < 16) {
      float acc = a.mc_b[ab];
      for (int i = 0; i < 16; ++i) acc += a.mc_w[ab * 16 + i] * S[MMAT + i * 16 + tid];
      S[SM + ab * 16 + tid] = fmaxf(acc, 0.f);
    }
    __syncthreads();
  }

  // weight = relu(max_fc_w @ [vA;vB] + max_fc_b); mi = argmax (first max)
  if (tid < 16) {
    float acc = a.max_fc_b[tid];
    for (int c = 0; c < 32; ++c) acc += a.max_fc_w[tid * 32 + c] * S[SM + c];
    S[SM + 32 + tid] = fmaxf(acc, 0.f);
  }
  __syncthreads();
  if (tid == 0) {
    float best = S[SM + 32];
    int mi = 0;
    for (int r = 1; r < 16; ++r) {
      float w = S[SM + 32 + r];
      if (w > best) { best = w; mi = r; }
    }
    if (mi > TDN - 1) mi = TDN - 1;   // jnp.take default mode clamps OOB
    S[SM + 48] = (float)mi;
  }
  __syncthreads();

  // ---- P3: wA_p, wB_p, eeg_ln ----------------------------------------
  {
    const int mi = (int)S[SM + 48];
    for (int o = tid; o < 16 * NOFC; o += NT) {
      int c = o / NOFC, t = o - c * NOFC;
      S[PA + o] = a.proj_w[c]      * S[WAVA + t + mi];
      S[PB + o] = a.proj_w[16 + c] * S[WAVB + t + mi];
    }
    for (int t = tid; t < NOFC; t += NT) {
      float mu = 0.f;
      for (int c = 0; c < 16; ++c) mu += S[EEGQ + c * NOFC + t];
      mu *= (1.0f / 16.0f);
      float var = 0.f;
      for (int c = 0; c < 16; ++c) {
        float d = S[EEGQ + c * NOFC + t] - mu;
        var += d * d;
      }
      var *= (1.0f / 16.0f);
      float inv = 1.0f / sqrtf(var + 1e-5f);
      for (int c = 0; c < 16; ++c)
        S[LNB + c * NOFC + t] = (S[EEGQ + c * NOFC + t] - mu) * inv * a.ln_g[c] + a.ln_b[c];
    }
  }
  __syncthreads();

  // ---- P4: four cm-MHAs (E=16), 119x119 attention streamed row-wise ---
  for (int i = 0; i < 4; ++i) {
    const int data_off = (i == 0) ? PA : (i == 3) ? PB : LNB;
    const int kv_off   = (i == 1) ? PA : (i == 2) ? PB : LNB;
    const float *inw = a.cm_in_w + i * 48 * 16;
    const float *inb = a.cm_in_b + i * 48;

    // qkv projections: [t][e] layouts, 16-MAC dots
    for (int o = tid; o < 3 * NOFC * 16; o += NT) {
      int which = o / (NOFC * 16);          // 0=q 1=k 2=v
      int rem = o - which * (NOFC * 16);
      int t = rem >> 4, e = rem & 15;
      int src = (which == 0) ? data_off : kv_off;
      const float *w = inw + (which * 16 + e) * 16;
      float acc = inb[which * 16 + e];
      for (int c = 0; c < 16; ++c) acc += S[src + c * NOFC + t] * w[c];
      S[(which == 0 ? CQ : which == 1 ? CK : CV) + rem] = acc;
    }
    __syncthreads();

    // attention: one row per 8-lane group (16 waves * 8 rows = 128 slots)
    {
      const int lane = tid & 63;
      const int wid  = tid >> 6;
      const int r    = wid * 8 + (lane >> 3);
      const int sub  = lane & 7;
      if (r < NOFC) {
        float p[15];
        float mx = -1e30f;
        for (int m = 0; m < 15; ++m) {
          int u = sub + m * 8;
          if (u < NOFC) {
            float acc = 0.f;
            for (int e = 0; e < 16; ++e) acc += S[CQ + r * 16 + e] * S[CK + u * 16 + e];
            p[m] = acc * 0.25f;
            mx = fmaxf(mx, p[m]);
          } else p[m] = -1e30f;
        }
        for (int d = 1; d < 8; d <<= 1) mx = fmaxf(mx, __shfl_xor(mx, d));
        float sum = 0.f;
        for (int m = 0; m < 15; ++m) {
          int u = sub + m * 8;
          p[m] = (u < NOFC) ? expf(p[m] - mx) : 0.f;
          sum += p[m];
        }
        for (int d = 1; d < 8; d <<= 1) sum += __shfl_xor(sum, d);
        float oa[16];
        for (int e = 0; e < 16; ++e) oa[e] = 0.f;
        for (int m = 0; m < 15; ++m) {
          int u = sub + m * 8;
          if (u < NOFC) {
            float pm = p[m];
            for (int e = 0; e < 16; ++e) oa[e] += pm * S[CV + u * 16 + e];
          }
        }
        float inv = 1.0f / sum;
        for (int e = 0; e < 16; ++e) {
          for (int d = 1; d < 8; d <<= 1) oa[e] += __shfl_xor(oa[e], d);
          oa[e] *= inv;
        }
        // out-projection: lane `sub` writes channels sub and sub+8
        const float *ow = a.cm_out_w + i * 256;
        const float *ob = a.cm_out_b + i * 16;
        const int dst = (i == 0 || i == 2) ? OKEEP : OCUR;
        for (int cc = 0; cc < 2; ++cc) {
          int c = sub + cc * 8;
          float acc = ob[c];
          for (int e = 0; e < 16; ++e) acc += oa[e] * ow[c * 16 + e];
          S[dst + r * 16 + c] = acc;
        }
      }
    }
    __syncthreads();

    if (i == 1 || i == 3) {
      // d0[t] = sum_c o0*o1 ; d1[t] = sum_c o3*o2
      for (int t = tid; t < NOFC; t += NT) {
        float acc = 0.f;
        for (int c = 0; c < 16; ++c) acc += S[OKEEP + t * 16 + c] * S[OCUR + t * 16 + c];
        S[DOF + (i == 1 ? 0 : NOFC) + t] = acc;
      }
      __syncthreads();
    }
  }

  // ---- P5: head -------------------------------------------------------
  for (int t = tid; t < 2 * NOFC; t += NT) {
    int half = t / NOFC;
    float v = a.fc_w[half] * S[DOF + t] + a.fc_b[half];
    S[DOF + t] = sigmf(v);
  }
  __syncthreads();
  for (int r = tid; r < NOFC; r += NT) {
    const float *w = a.out1_w + r * 2 * NOFC;
    float acc = a.out1_b[r];
    for (int c = 0; c < 2 * NOFC; ++c) acc += w[c] * S[DOF + c];
    S[HOF + r] = sigmf(acc);
  }
  __syncthreads();
  if (tid < 2) {
    float acc = a.out2_b[tid];
    for (int r = 0; r < NOFC; ++r) acc += a.out2_w[tid * NOFC + r] * S[HOF + r];
    a.out[tid] = sigmf(acc);
  }
}

extern "C" void kernel_launch(void* const* d_in, const int* in_sizes, int n_in,
                              void* d_out, int out_size, void* d_ws, size_t ws_size,
                              hipStream_t stream) {
  Args a;
  a.x        = (const float*)d_in[0];
  a.td_in_w  = (const float*)d_in[1];
  a.td_in_b  = (const float*)d_in[2];
  a.td_out_w = (const float*)d_in[3];
  a.td_out_b = (const float*)d_in[4];
  a.cm_in_w  = (const float*)d_in[5];
  a.cm_in_b  = (const float*)d_in[6];
  a.cm_out_w = (const float*)d_in[7];
  a.cm_out_b = (const float*)d_in[8];
  a.mc_w     = (const float*)d_in[9];
  a.mc_b     = (const float*)d_in[10];
  a.max_fc_w = (const float*)d_in[11];
  a.max_fc_b = (const float*)d_in[12];
  a.proj_w   = (const float*)d_in[13];
  a.ln_g     = (const float*)d_in[14];
  a.ln_b     = (const float*)d_in[15];
  a.fc_w     = (const float*)d_in[16];
  a.fc_b     = (const float*)d_in[17];
  a.out1_w   = (const float*)d_in[18];
  a.out1_b   = (const float*)d_in[19];
  a.out2_w   = (const float*)d_in[20];
  a.out2_b   = (const float*)d_in[21];
  a.out      = (float*)d_out;

  fused_cnn_kernel<<<1, NT, 0, stream>>>(a);
}

// Round 2
// 166.808 us; speedup vs baseline: 1.2578x; 1.2578x over previous
//
#include <hip/hip_runtime.h>
#include <math.h>

// ---------------------------------------------------------------------------
// CNN_88098369175791 — fused single-block, latency-optimized rewrite.
//  * 119-dots: 16-lane-group coalesced weight reads + shuffle reduce
//  * cm-attention: 16 q-rows/wave, 4-lane col split, K/V float4 broadcast
//  * 2 cm-MHAs processed concurrently (16 waves busy), 112KB LDS arena
// ---------------------------------------------------------------------------

#define NT 1024

constexpr int WLEN = 140;
constexpr int TDN  = 14;
constexpr int NOFC = 119;

// ---- LDS arena (floats), regions time-multiplexed --------------------------
constexpr int EEGQ = 0;      // [16][119]  live P0..LN
constexpr int WAVA = 1904;   // 140        live P0..P3
constexpr int WAVB = 2044;   // 140
constexpr int QP   = 2184;   // [16][119]  dead after td-scores
constexpr int KP   = 4088;   // [2][14][119] dead after td-scores
constexpr int VP   = 7420;   // [2][14][119] dead after av
constexpr int ATT  = 10752;  // [2][16][14]  dead after av
constexpr int AV   = 11200;  // [2][16][119] dead after watt
constexpr int WATT = 2184;   // [2][16][119] reuse QP+KP (dead)
constexpr int MM   = 5992;   // [2][16][16]
constexpr int SMB  = 6504;   // vA[16] vB[16] weight[16] mi -> 64
// phase B (after argmax):
constexpr int PAT  = 7420;   // [119][16]  (over VP, dead)
constexpr int PBT  = 9324;   // [119][16]
constexpr int LNT  = 11228;  // [119][16]  (over AV, dead)
constexpr int CQ   = 13132;  // [2][119][16] pair of MHAs
constexpr int CK   = 16940;  // [2][119][16]
constexpr int CV   = 20748;  // [2][119][16]
constexpr int OO   = 24556;  // [2][119][16]
constexpr int DOF  = 28364;  // 238
constexpr int HOF  = 28602;  // 119
constexpr int ARENA = 28736; // 114,944 B  (< 160 KiB gfx950 LDS)

struct Args {
  const float *x, *td_in_w, *td_in_b, *td_out_w, *td_out_b;
  const float *cm_in_w, *cm_in_b, *cm_out_w, *cm_out_b;
  const float *mc_w, *mc_b, *max_fc_w, *max_fc_b, *proj_w;
  const float *ln_g, *ln_b, *fc_w, *fc_b;
  const float *out1_w, *out1_b, *out2_w, *out2_b;
  float *out;
};

__device__ __forceinline__ float sigmf(float v) {
  return 1.0f / (1.0f + __expf(-v));
}

// 119-dot split over a 16-lane group; both pointers may be LDS or global.
// Returns full sum in ALL 16 lanes.
__device__ __forceinline__ float dot119(const float* __restrict__ w,
                                        const float* __restrict__ x,
                                        int lane16) {
  float a0 = 0.f, a1 = 0.f;
#pragma unroll
  for (int t = 0; t < 7; ++t) {
    float wv = w[lane16 + 16 * t];
    float xv = x[lane16 + 16 * t];
    if (t & 1) a1 += wv * xv; else a0 += wv * xv;
  }
  if (lane16 < 7) a0 += w[112 + lane16] * x[112 + lane16];
  float acc = a0 + a1;
#pragma unroll
  for (int m = 1; m < 16; m <<= 1) acc += __shfl_xor(acc, m);
  return acc;
}

__global__ __launch_bounds__(NT) void fused_cnn_kernel(Args a) {
  __shared__ float S[ARENA];
  const int tid = threadIdx.x;
  const int grp16 = tid >> 4;      // 64 groups of 16 lanes
  const int lane16 = tid & 15;

  // ---- P0: stage inputs ------------------------------------------------
  for (int t = tid; t < 16 * NOFC; t += NT) {
    int c = t / NOFC, tt = t - c * NOFC;
    S[EEGQ + t] = a.x[(1 + c) * WLEN + (WLEN - NOFC) + tt];
  }
  if (tid < WLEN) {
    S[WAVA + tid] = a.x[tid];
    S[WAVB + tid] = a.x[17 * WLEN + tid];
  }
  __syncthreads();

  // ---- P1: merged td projections (qp, kpA, vpA, kpB, vpB) --------------
  // 8568 outputs, each = 119-dot(td_in_w row, LDS activation)
  for (int o = grp16; o < 8568; o += 64) {
    int row, act, dst;
    if (o < 1904) {               // qp[i][e], i-major
      int i = o / NOFC, e = o - i * NOFC;
      row = e; act = EEGQ + i * NOFC; dst = QP + o;
    } else if (o < 5236) {        // kp[ab][j][e]
      int id2 = o - 1904;
      int ab = id2 / 1666, rem = id2 - ab * 1666;
      int j = rem / NOFC, e = rem - j * NOFC;
      row = NOFC + e; act = (ab ? WAVB : WAVA) + j; dst = KP + id2;
    } else {                      // vp[ab][j][e]
      int id2 = o - 5236;
      int ab = id2 / 1666, rem = id2 - ab * 1666;
      int j = rem / NOFC, e = rem - j * NOFC;
      row = 2 * NOFC + e; act = (ab ? WAVB : WAVA) + j; dst = VP + id2;
    }
    float acc = dot119(a.td_in_w + row * NOFC, S + act, lane16);
    if (lane16 == 0) S[dst] = acc + a.td_in_b[row];
  }
  __syncthreads();

  // ---- td scores: [2][16][14], 119-dot, scale 119^-0.5 -----------------
  for (int o = grp16; o < 448; o += 64) {
    int ab = o / 224, rem = o - ab * 224;
    int i = rem / TDN, j = rem - i * TDN;
    float acc = dot119(S + QP + i * NOFC, S + KP + ab * 1666 + j * NOFC, lane16);
    if (lane16 == 0) S[ATT + o] = acc * 0.09166984970282113f;
  }
  __syncthreads();

  // ---- td softmax (32 rows of 14) --------------------------------------
  if (tid < 32) {
    float* r = S + ATT + tid * TDN;
    float m = r[0];
#pragma unroll
    for (int j = 1; j < TDN; ++j) m = fmaxf(m, r[j]);
    float sum = 0.f;
#pragma unroll
    for (int j = 0; j < TDN; ++j) { float p = __expf(r[j] - m); r[j] = p; sum += p; }
    float inv = 1.0f / sum;
#pragma unroll
    for (int j = 0; j < TDN; ++j) r[j] *= inv;
  }
  __syncthreads();

  // ---- av = attn @ vp : [2][16][119], 14-dot, per-thread ---------------
  for (int o = tid; o < 3808; o += NT) {
    int ab = o / 1904, rem = o - ab * 1904;
    int i = rem / NOFC, e = rem - i * NOFC;
    const float* at = S + ATT + ab * 224 + i * TDN;
    const float* vp = S + VP + ab * 1666 + e;
    float acc = 0.f;
#pragma unroll
    for (int j = 0; j < TDN; ++j) acc += at[j] * vp[j * NOFC];
    S[AV + o] = acc;
  }
  __syncthreads();

  // ---- watt = av @ out_w^T + b : [2][16][119], 119-dot -----------------
  for (int o = grp16; o < 3808; o += 64) {
    int ab = o / 1904, rem = o - ab * 1904;
    int k = rem / NOFC, e = rem - k * NOFC;
    float acc = dot119(a.td_out_w + e * NOFC, S + AV + ab * 1904 + k * NOFC, lane16);
    if (lane16 == 0) S[WATT + o] = acc + a.td_out_b[e];
  }
  __syncthreads();

  // ---- M[ab][i][k] = eeg[i] . watt[ab][k] : 512 outs, 119-dot ----------
  for (int o = grp16; o < 512; o += 64) {
    int ab = o >> 8, i = (o >> 4) & 15, k = o & 15;
    float acc = dot119(S + EEGQ + i * NOFC, S + WATT + ab * 1904 + k * NOFC, lane16);
    if (lane16 == 0) S[MM + o] = acc;
  }
  __syncthreads();

  // ---- vA/vB then weight fc --------------------------------------------
  if (tid < 32) {
    int ab = tid >> 4, kk = tid & 15;
    float acc = a.mc_b[ab];
#pragma unroll
    for (int i = 0; i < 16; ++i) acc += a.mc_w[ab * 16 + i] * S[MM + ab * 256 + i * 16 + kk];
    S[SMB + ab * 16 + kk] = fmaxf(acc, 0.f);
  }
  __syncthreads();
  if (tid < 16) {
    float acc = a.max_fc_b[tid];
#pragma unroll
    for (int c = 0; c < 32; ++c) acc += a.max_fc_w[tid * 32 + c] * S[SMB + c];
    S[SMB + 32 + tid] = fmaxf(acc, 0.f);
  }
  __syncthreads();
  if (tid == 0) {
    float best = S[SMB + 32]; int mi = 0;
    for (int r = 1; r < 16; ++r) {
      float w = S[SMB + 32 + r];
      if (w > best) { best = w; mi = r; }
    }
    if (mi > TDN - 1) mi = TDN - 1;   // jnp.take clamps OOB
    S[SMB + 48] = (float)mi;
  }
  __syncthreads();

  // ---- P3: PAT/PBT ([t][16]) and LNT ([t][16]) -------------------------
  {
    const int mi = (int)S[SMB + 48];
    for (int o = tid; o < 3808; o += NT) {
      int ab = o / 1904, r2 = o - ab * 1904;
      int t = r2 >> 4, c = r2 & 15;
      float v = a.proj_w[ab * 16 + c] * S[(ab ? WAVB : WAVA) + t + mi];
      S[(ab ? PBT : PAT) + r2] = v;
    }
    if (tid < NOFC) {
      float xv[16];
      float mu = 0.f;
#pragma unroll
      for (int c = 0; c < 16; ++c) { xv[c] = S[EEGQ + c * NOFC + tid]; mu += xv[c]; }
      mu *= (1.0f / 16.0f);
      float var = 0.f;
#pragma unroll
      for (int c = 0; c < 16; ++c) { float d = xv[c] - mu; var += d * d; }
      var *= (1.0f / 16.0f);
      float inv = 1.0f / sqrtf(var + 1e-5f);
#pragma unroll
      for (int c = 0; c < 16; ++c)
        S[LNT + tid * 16 + c] = (xv[c] - mu) * inv * a.ln_g[c] + a.ln_b[c];
    }
  }
  __syncthreads();

  // ---- P4: four cm-MHAs, two at a time ---------------------------------
  const int lane = tid & 63, wv = tid >> 6;
  const int i4 = lane >> 2, s4 = lane & 3;

  for (int pp = 0; pp < 2; ++pp) {
    // qkv projections for MHAs m = 2pp, 2pp+1  (11424 outs, 16-dot, float4)
    for (int o = tid; o < 11424; o += NT) {
      int half = o / 5712, r1 = o - half * 5712;
      int which = r1 / 1904, r2 = r1 - which * 1904;
      int t = r2 >> 4, e = r2 & 15;
      int m = pp * 2 + half;
      int src;
      if (which == 0) src = (m == 0) ? PAT : (m == 3) ? PBT : LNT;   // data
      else            src = (m == 1) ? PAT : (m == 2) ? PBT : LNT;   // kv
      const float4* sa = (const float4*)(S + src + t * 16);
      const float4* wr = (const float4*)(a.cm_in_w + (m * 48 + which * 16 + e) * 16);
      float4 s0 = sa[0], s1 = sa[1], s2 = sa[2], s3 = sa[3];
      float4 w0 = wr[0], w1 = wr[1], w2 = wr[2], w3 = wr[3];
      float d0 = s0.x * w0.x + s0.y * w0.y + s0.z * w0.z + s0.w * w0.w;
      float d1 = s1.x * w1.x + s1.y * w1.y + s1.z * w1.z + s1.w * w1.w;
      float d2 = s2.x * w2.x + s2.y * w2.y + s2.z * w2.z + s2.w * w2.w;
      float d3 = s3.x * w3.x + s3.y * w3.y + s3.z * w3.z + s3.w * w3.w;
      float acc = a.cm_in_b[m * 48 + which * 16 + e] + ((d0 + d1) + (d2 + d3));
      int dst = (which == 0 ? CQ : which == 1 ? CK : CV) + half * 1904 + r2;
      S[dst] = acc;
    }
    __syncthreads();

    // attention: wave wv handles 16 q-rows (slot = wv*16+i4), 4-lane col split
    {
      int slot = wv * 16 + i4;          // [0,256)
      int m2 = slot >> 7;               // which MHA of the pair
      int r = slot & 127;
      bool valid = r < NOFC;
      int rc = valid ? r : NOFC - 1;
      int m = pp * 2 + m2;

      float qv[16];
      {
        const float4* q4 = (const float4*)(S + CQ + (m2 * NOFC + rc) * 16);
        *(float4*)(qv + 0)  = q4[0];
        *(float4*)(qv + 4)  = q4[1];
        *(float4*)(qv + 8)  = q4[2];
        *(float4*)(qv + 12) = q4[3];
      }

      float p[30];
      float mx = -1e30f;
#pragma unroll
      for (int cc = 0; cc < 30; ++cc) {
        int u = s4 + cc * 4;
        int uc = (u < NOFC) ? u : 0;
        const float4* k4 = (const float4*)(S + CK + (m2 * NOFC + uc) * 16);
        float kv[16];
        *(float4*)(kv + 0)  = k4[0];
        *(float4*)(kv + 4)  = k4[1];
        *(float4*)(kv + 8)  = k4[2];
        *(float4*)(kv + 12) = k4[3];
        float d0 = 0.f, d1 = 0.f, d2 = 0.f, d3 = 0.f;
#pragma unroll
        for (int e = 0; e < 16; e += 4) {
          d0 += qv[e] * kv[e];
          d1 += qv[e + 1] * kv[e + 1];
          d2 += qv[e + 2] * kv[e + 2];
          d3 += qv[e + 3] * kv[e + 3];
        }
        float sc = ((d0 + d1) + (d2 + d3)) * 0.25f;
        p[cc] = (u < NOFC) ? sc : -1e30f;
        mx = fmaxf(mx, p[cc]);
      }
      mx = fmaxf(mx, __shfl_xor(mx, 1));
      mx = fmaxf(mx, __shfl_xor(mx, 2));
      float sum = 0.f;
#pragma unroll
      for (int cc = 0; cc < 30; ++cc) { p[cc] = __expf(p[cc] - mx); sum += p[cc]; }
      sum += __shfl_xor(sum, 1);
      sum += __shfl_xor(sum, 2);
      float inv = 1.0f / sum;

      float oa[16];
#pragma unroll
      for (int e = 0; e < 16; ++e) oa[e] = 0.f;
#pragma unroll
      for (int cc = 0; cc < 30; ++cc) {
        int u = s4 + cc * 4;
        int uc = (u < NOFC) ? u : 0;
        const float4* v4 = (const float4*)(S + CV + (m2 * NOFC + uc) * 16);
        float vv[16];
        *(float4*)(vv + 0)  = v4[0];
        *(float4*)(vv + 4)  = v4[1];
        *(float4*)(vv + 8)  = v4[2];
        *(float4*)(vv + 12) = v4[3];
        float pv = p[cc];
#pragma unroll
        for (int e = 0; e < 16; ++e) oa[e] += pv * vv[e];
      }
#pragma unroll
      for (int e = 0; e < 16; ++e) {
        oa[e] += __shfl_xor(oa[e], 1);
        oa[e] += __shfl_xor(oa[e], 2);
        oa[e] *= inv;
      }
      // out-projection: lane s4 writes channels {s4, s4+4, s4+8, s4+12}
      if (valid) {
        const float* ow = a.cm_out_w + m * 256;
        const float* ob = a.cm_out_b + m * 16;
#pragma unroll
        for (int k = 0; k < 4; ++k) {
          int c = s4 + k * 4;
          const float* wr = ow + c * 16;
          float acc = ob[c];
#pragma unroll
          for (int e = 0; e < 16; ++e) acc += oa[e] * wr[e];
          S[OO + (m2 * NOFC + r) * 16 + c] = acc;
        }
      }
    }
    __syncthreads();

    // d[pp][t] = sum_c O_slot0[t][c] * O_slot1[t][c]
    if (tid < NOFC) {
      float acc = 0.f;
#pragma unroll
      for (int c = 0; c < 16; ++c)
        acc += S[OO + tid * 16 + c] * S[OO + 1904 + tid * 16 + c];
      S[DOF + pp * NOFC + tid] = acc;
    }
    __syncthreads();
  }

  // ---- P5: head --------------------------------------------------------
  if (tid < 2 * NOFC) {
    int half = tid / NOFC;
    S[DOF + tid] = sigmf(a.fc_w[half] * S[DOF + tid] + a.fc_b[half]);
  }
  __syncthreads();
  // h[r] = sigm(out1_w[r,:238] . dd + b) — 238-dot over 16 lanes
  for (int o = grp16; o < NOFC; o += 64) {
    const float* wrow = a.out1_w + o * 238;
    float a0 = 0.f, a1 = 0.f;
#pragma unroll
    for (int t = 0; t < 14; ++t) {
      float wv = wrow[lane16 + 16 * t];
      float xv = S[DOF + lane16 + 16 * t];
      if (t & 1) a1 += wv * xv; else a0 += wv * xv;
    }
    if (lane16 < 14) a0 += wrow[224 + lane16] * S[DOF + 224 + lane16];
    float acc = a0 + a1;
#pragma unroll
    for (int m = 1; m < 16; m <<= 1) acc += __shfl_xor(acc, m);
    if (lane16 == 0) S[HOF + o] = sigmf(acc + a.out1_b[o]);
  }
  __syncthreads();
  // out[2] = sigm(out2_w @ h + b) — two 119-dots over 16 lanes each
  if (tid < 32) {
    int o2 = tid >> 4;
    const float* wrow = a.out2_w + o2 * NOFC;
    float a0 = 0.f;
#pragma unroll
    for (int t = 0; t < 8; ++t) {
      int idx = lane16 + 16 * t;
      if (idx < NOFC) a0 += wrow[idx] * S[HOF + idx];
    }
    float acc = a0;
#pragma unroll
    for (int m = 1; m < 16; m <<= 1) acc += __shfl_xor(acc, m);
    if (lane16 == 0) a.out[o2] = sigmf(acc + a.out2_b[o2]);
  }
}

extern "C" void kernel_launch(void* const* d_in, const int* in_sizes, int n_in,
                              void* d_out, int out_size, void* d_ws, size_t ws_size,
                              hipStream_t stream) {
  Args a;
  a.x        = (const float*)d_in[0];
  a.td_in_w  = (const float*)d_in[1];
  a.td_in_b  = (const float*)d_in[2];
  a.td_out_w = (const float*)d_in[3];
  a.td_out_b = (const float*)d_in[4];
  a.cm_in_w  = (const float*)d_in[5];
  a.cm_in_b  = (const float*)d_in[6];
  a.cm_out_w = (const float*)d_in[7];
  a.cm_out_b = (const float*)d_in[8];
  a.mc_w     = (const float*)d_in[9];
  a.mc_b     = (const float*)d_in[10];
  a.max_fc_w = (const float*)d_in[11];
  a.max_fc_b = (const float*)d_in[12];
  a.proj_w   = (const float*)d_in[13];
  a.ln_g     = (const float*)d_in[14];
  a.ln_b     = (const float*)d_in[15];
  a.fc_w     = (const float*)d_in[16];
  a.fc_b     = (const float*)d_in[17];
  a.out1_w   = (const float*)d_in[18];
  a.out1_b   = (const float*)d_in[19];
  a.out2_w   = (const float*)d_in[20];
  a.out2_b   = (const float*)d_in[21];
  a.out      = (float*)d_out;

  fused_cnn_kernel<<<1, NT, 0, stream>>>(a);
}

// Round 3
// 49.553 us; speedup vs baseline: 4.2340x; 3.3662x over previous
//
#include <hip/hip_runtime.h>
#include <math.h>

// ---------------------------------------------------------------------------
// CNN_88098369175791 — 8-workgroup distributed version.
// One CU was VALU-issue-bound (~50% busy, 172us). Phases are distributed
// across 8 WGs (8 CUs) with 5 device-scope grid barriers through a global
// arena in d_ws. Tiny phases (softmax/argmax/LN/head) are replicated.
// Barrier counters are zeroed each call via hipMemsetAsync (graph-safe).
// ---------------------------------------------------------------------------

#define NWG 8
#define NT  1024

constexpr int WLEN = 140;
constexpr int TDN  = 14;
constexpr int NOFC = 119;

// ---------------- global arena (floats; at d_ws + 512 B) -------------------
constexpr int G_QP   = 0;      // [16][119]
constexpr int G_KP   = 1904;   // [2][14][119]
constexpr int G_VP   = 5236;   // [2][14][119]
constexpr int G_WATT = 8568;   // [2][16][119]
constexpr int G_V16  = 12376;  // [32]  vA|vB
constexpr int G_CQ   = 12416;  // [4][119][16]
constexpr int G_CK   = 20032;  // [4][119][16]
constexpr int G_CV   = 27648;  // [4][119][16]
constexpr int G_O    = 35264;  // [4][119][16] -> ends 42880 (171.5 KB)

// ---------------- LDS arena (floats, regions time-multiplexed) -------------
constexpr int EEG = 0;     // [16][119] live all phases
constexpr int WA  = 1904;  // 140
constexpr int WB  = 2044;  // 140
// rows-phase scratch:
constexpr int KPL = 2184;  // [14][119]
constexpr int VPL = 3850;  // [14][119]
constexpr int QPL = 5516;  // [4][119]
constexpr int SC  = 5992;  // [4][14]
constexpr int AVL = 6048;  // [4][119] -> 6524
constexpr int MM  = 6524;  // [4][16]
// post-argmax (over rows-phase scratch):
constexpr int PAT = 2184;  // [119][16]
constexpr int PBT = 4088;  // [119][16]
constexpr int LNT = 5992;  // [119][16] -> 7896
// attention phase (over PAT/PBT, stride-20 rows to dodge bank conflicts):
constexpr int CKL = 2184;  // [119][20] -> 4564
constexpr int CVL = 4564;  // [119][20] -> 6944
// head (WG0):
constexpr int DD  = 2184;  // 238
constexpr int HH  = 2422;  // 119
constexpr int SMB = 7900;  // weight[16]; mi at +16
constexpr int ARENA = 7936;  // 31,744 B

struct Args {
  const float *x, *td_in_w, *td_in_b, *td_out_w, *td_out_b;
  const float *cm_in_w, *cm_in_b, *cm_out_w, *cm_out_b;
  const float *mc_w, *mc_b, *max_fc_w, *max_fc_b, *proj_w;
  const float *ln_g, *ln_b, *fc_w, *fc_b;
  const float *out1_w, *out1_b, *out2_w, *out2_b;
  float *out;
  unsigned int *bar;   // d_ws (5 sites x 64B, memset to 0 per call)
  float *G;            // d_ws + 512
};

__device__ __forceinline__ float sigmf(float v) {
  return 1.0f / (1.0f + __expf(-v));
}

// grid barrier: all prior stores of all WGs are in L2 after __syncthreads
// (compiler drains vmcnt before s_barrier); tid0's release fence writes L2
// back to the device coherence point; acquire load invalidates stale lines.
__device__ __forceinline__ void gbar(unsigned int* bar, int site) {
  __syncthreads();
  if (threadIdx.x == 0) {
    __threadfence();                                   // release
    unsigned int* p = bar + site * 16;
    __hip_atomic_fetch_add(p, 1u, __ATOMIC_ACQ_REL, __HIP_MEMORY_SCOPE_AGENT);
    while (__hip_atomic_load(p, __ATOMIC_ACQUIRE, __HIP_MEMORY_SCOPE_AGENT) < (unsigned)NWG) {
      __builtin_amdgcn_s_sleep(2);
    }
  }
  __syncthreads();
}

// 119-dot over a 16-lane group; result in ALL 16 lanes.
__device__ __forceinline__ float dot119(const float* __restrict__ w,
                                        const float* __restrict__ x,
                                        int lane16) {
  float a0 = 0.f, a1 = 0.f;
#pragma unroll
  for (int t = 0; t < 7; ++t) {
    float wv = w[lane16 + 16 * t];
    float xv = x[lane16 + 16 * t];
    if (t & 1) a1 += wv * xv; else a0 += wv * xv;
  }
  if (lane16 < 7) a0 += w[112 + lane16] * x[112 + lane16];
  float acc = a0 + a1;
#pragma unroll
  for (int m = 1; m < 16; m <<= 1) acc += __shfl_xor(acc, m);
  return acc;
}

__global__ __launch_bounds__(NT) void fused_cnn_kernel(Args a) {
  __shared__ __align__(16) float S[ARENA];
  const int tid = threadIdx.x;
  const int wgid = blockIdx.x;
  const int grp = tid >> 4;        // 64 groups of 16
  const int lane16 = tid & 15;
  float* G = a.G;

  // ---- P0: every WG stages eeg_q, wavA, wavB --------------------------
  for (int t = tid; t < 16 * NOFC; t += NT) {
    int c = t / NOFC, tt = t - c * NOFC;
    S[EEG + t] = a.x[(1 + c) * WLEN + (WLEN - NOFC) + tt];
  }
  if (tid < WLEN) {
    S[WA + tid] = a.x[tid];
    S[WB + tid] = a.x[17 * WLEN + tid];
  }
  __syncthreads();

  // ---- P1 (distributed): qp/kp/vp -> global ---------------------------
  for (int o = wgid * 64 + grp; o < 8568; o += NWG * 64) {
    int row, act, dst;
    if (o < 1904) {               // qp[i][e]
      int i = o / NOFC, e = o - i * NOFC;
      row = e; act = EEG + i * NOFC; dst = G_QP + o;
    } else if (o < 5236) {        // kp[ab][j][e]
      int id2 = o - 1904;
      int ab = id2 / 1666, rem = id2 - ab * 1666;
      int j = rem / NOFC, e = rem - j * NOFC;
      row = NOFC + e; act = (ab ? WB : WA) + j; dst = G_KP + id2;
    } else {                      // vp[ab][j][e]
      int id2 = o - 5236;
      int ab = id2 / 1666, rem = id2 - ab * 1666;
      int j = rem / NOFC, e = rem - j * NOFC;
      row = 2 * NOFC + e; act = (ab ? WB : WA) + j; dst = G_VP + id2;
    }
    float acc = dot119(a.td_in_w + row * NOFC, S + act, lane16);
    if (lane16 == 0) G[dst] = acc + a.td_in_b[row];
  }
  gbar(a.bar, 0);

  // ---- rows phase (distributed): each WG owns 4 attention rows --------
  {
    const int ab = wgid >> 2;          // WG 0-3: A, 4-7: B
    const int i0 = (wgid * 4) & 15;    // first of 4 q-rows
    for (int t = tid; t < 1666; t += NT) {
      S[KPL + t] = G[G_KP + ab * 1666 + t];
      S[VPL + t] = G[G_VP + ab * 1666 + t];
    }
    for (int t = tid; t < 476; t += NT) S[QPL + t] = G[G_QP + i0 * NOFC + t];
    __syncthreads();

    if (grp < 56) {                    // scores: 4 rows x 14 cols
      int q = grp / TDN, j = grp - q * TDN;
      float acc = dot119(S + QPL + q * NOFC, S + KPL + j * NOFC, lane16);
      if (lane16 == 0) S[SC + q * TDN + j] = acc * 0.09166984970282113f;
    }
    __syncthreads();

    if (tid < 4) {                     // softmax rows
      float* r = S + SC + tid * TDN;
      float m = r[0];
#pragma unroll
      for (int j = 1; j < TDN; ++j) m = fmaxf(m, r[j]);
      float sum = 0.f;
#pragma unroll
      for (int j = 0; j < TDN; ++j) { float p = __expf(r[j] - m); r[j] = p; sum += p; }
      float inv = 1.0f / sum;
#pragma unroll
      for (int j = 0; j < TDN; ++j) r[j] *= inv;
    }
    __syncthreads();

    for (int o = tid; o < 476; o += NT) {   // av = attn @ vp
      int q = o / NOFC, e = o - q * NOFC;
      float acc = 0.f;
#pragma unroll
      for (int j = 0; j < TDN; ++j) acc += S[SC + q * TDN + j] * S[VPL + j * NOFC + e];
      S[AVL + o] = acc;
    }
    __syncthreads();

    for (int o = grp; o < 476; o += 64) {   // watt rows -> global
      int q = o / NOFC, e = o - q * NOFC;
      float acc = dot119(a.td_out_w + e * NOFC, S + AVL + q * NOFC, lane16);
      if (lane16 == 0)
        G[G_WATT + (ab * 16 + i0 + q) * NOFC + e] = acc + a.td_out_b[e];
    }
  }
  gbar(a.bar, 1);

  // ---- M columns + vA/vB (distributed: 4 cols per WG) -----------------
  {
    const int ab = wgid >> 2;
    const int k0 = (wgid * 4) & 15;
    {
      int q = grp >> 4, i = grp & 15;       // 64 dots exactly
      float acc = dot119(S + EEG + i * NOFC,
                         G + G_WATT + (ab * 16 + k0 + q) * NOFC, lane16);
      if (lane16 == 0) S[MM + q * 16 + i] = acc;
    }
    __syncthreads();
    if (tid < 4) {
      float acc = a.mc_b[ab];
#pragma unroll
      for (int i = 0; i < 16; ++i) acc += a.mc_w[ab * 16 + i] * S[MM + tid * 16 + i];
      G[G_V16 + ab * 16 + k0 + tid] = fmaxf(acc, 0.f);
    }
  }
  gbar(a.bar, 2);

  // ---- weight + argmax (replicated; identical in every WG) ------------
  if (tid < 16) {
    float acc = a.max_fc_b[tid];
#pragma unroll
    for (int c = 0; c < 32; ++c) acc += a.max_fc_w[tid * 32 + c] * G[G_V16 + c];
    S[SMB + tid] = fmaxf(acc, 0.f);
  }
  __syncthreads();
  if (tid == 0) {
    float best = S[SMB]; int mi = 0;
    for (int r = 1; r < 16; ++r) {
      float w = S[SMB + r];
      if (w > best) { best = w; mi = r; }
    }
    if (mi > TDN - 1) mi = TDN - 1;   // jnp.take clamps OOB
    S[SMB + 16] = (float)mi;
  }
  __syncthreads();

  // ---- P3 (replicated): PAT/PBT ([t][16]) and LNT ([t][16]) -----------
  {
    const int mi = (int)S[SMB + 16];
    for (int o = tid; o < 3808; o += NT) {
      int ab = o / 1904, r2 = o - ab * 1904;
      int t = r2 >> 4, c = r2 & 15;
      S[(ab ? PBT : PAT) + r2] = a.proj_w[ab * 16 + c] * S[(ab ? WB : WA) + t + mi];
    }
    if (tid < NOFC) {
      float xv[16];
      float mu = 0.f;
#pragma unroll
      for (int c = 0; c < 16; ++c) { xv[c] = S[EEG + c * NOFC + tid]; mu += xv[c]; }
      mu *= (1.0f / 16.0f);
      float var = 0.f;
#pragma unroll
      for (int c = 0; c < 16; ++c) { float d = xv[c] - mu; var += d * d; }
      var *= (1.0f / 16.0f);
      float inv = 1.0f / sqrtf(var + 1e-5f);
#pragma unroll
      for (int c = 0; c < 16; ++c)
        S[LNT + tid * 16 + c] = (xv[c] - mu) * inv * a.ln_g[c] + a.ln_b[c];
    }
  }
  __syncthreads();

  // ---- cm qkv projections (distributed) -> global ---------------------
  for (int o = wgid * NT + tid; o < 22848; o += NWG * NT) {
    int m = o / 5712, r1 = o - m * 5712;
    int which = r1 / 1904, r2 = r1 - which * 1904;
    int t = r2 >> 4, e = r2 & 15;
    int src;
    if (which == 0) src = (m == 0) ? PAT : (m == 3) ? PBT : LNT;   // data
    else            src = (m == 1) ? PAT : (m == 2) ? PBT : LNT;   // kv
    const float4* sa = (const float4*)(S + src + t * 16);
    const float4* wr = (const float4*)(a.cm_in_w + (m * 48 + which * 16 + e) * 16);
    float4 s0 = sa[0], s1 = sa[1], s2 = sa[2], s3 = sa[3];
    float4 w0 = wr[0], w1 = wr[1], w2 = wr[2], w3 = wr[3];
    float d0 = s0.x * w0.x + s0.y * w0.y + s0.z * w0.z + s0.w * w0.w;
    float d1 = s1.x * w1.x + s1.y * w1.y + s1.z * w1.z + s1.w * w1.w;
    float d2 = s2.x * w2.x + s2.y * w2.y + s2.z * w2.z + s2.w * w2.w;
    float d3 = s3.x * w3.x + s3.y * w3.y + s3.z * w3.z + s3.w * w3.w;
    float acc = a.cm_in_b[m * 48 + which * 16 + e] + ((d0 + d1) + (d2 + d3));
    G[(which == 0 ? G_CQ : which == 1 ? G_CK : G_CV) + m * 1904 + r2] = acc;
  }
  gbar(a.bar, 3);

  // ---- cm attention (distributed: 2 WGs per MHA, ~60 rows each) -------
  {
    const int m = wgid >> 1;
    const int r0 = (wgid & 1) ? 60 : 0;
    const int nr = (wgid & 1) ? 59 : 60;
    for (int t = tid; t < 1904; t += NT) {       // stage K,V (stride-20 rows)
      int r = t >> 4, e = t & 15;
      S[CKL + r * 20 + e] = G[G_CK + m * 1904 + t];
      S[CVL + r * 20 + e] = G[G_CV + m * 1904 + t];
    }
    __syncthreads();

    if (grp < nr) {
      const int r = r0 + grp;
      float qv[16];
      {
        const float* qg = G + G_CQ + (m * NOFC + r) * 16;
#pragma unroll
        for (int e = 0; e < 16; ++e) qv[e] = qg[e];
      }
      float p[8];
      float mx = -1e30f;
#pragma unroll
      for (int cc = 0; cc < 8; ++cc) {
        int u = lane16 + cc * 16;
        int uc = (u < NOFC) ? u : 0;
        const float4* k4 = (const float4*)(S + CKL + uc * 20);
        float4 k0 = k4[0], k1 = k4[1], k2 = k4[2], k3 = k4[3];
        float d0 = qv[0]*k0.x + qv[1]*k0.y + qv[2]*k0.z + qv[3]*k0.w;
        float d1 = qv[4]*k1.x + qv[5]*k1.y + qv[6]*k1.z + qv[7]*k1.w;
        float d2 = qv[8]*k2.x + qv[9]*k2.y + qv[10]*k2.z + qv[11]*k2.w;
        float d3 = qv[12]*k3.x + qv[13]*k3.y + qv[14]*k3.z + qv[15]*k3.w;
        float sc = ((d0 + d1) + (d2 + d3)) * 0.25f;
        p[cc] = (u < NOFC) ? sc : -1e30f;
        mx = fmaxf(mx, p[cc]);
      }
#pragma unroll
      for (int d = 1; d < 16; d <<= 1) mx = fmaxf(mx, __shfl_xor(mx, d));
      float sum = 0.f;
#pragma unroll
      for (int cc = 0; cc < 8; ++cc) { p[cc] = __expf(p[cc] - mx); sum += p[cc]; }
#pragma unroll
      for (int d = 1; d < 16; d <<= 1) sum += __shfl_xor(sum, d);
      float inv = 1.0f / sum;

      float oa[16];
#pragma unroll
      for (int e = 0; e < 16; ++e) oa[e] = 0.f;
#pragma unroll
      for (int cc = 0; cc < 8; ++cc) {
        int u = lane16 + cc * 16;
        if (u < NOFC) {
          const float4* v4 = (const float4*)(S + CVL + u * 20);
          float4 v0 = v4[0], v1 = v4[1], v2 = v4[2], v3 = v4[3];
          float pv = p[cc];
          oa[0] += pv*v0.x; oa[1] += pv*v0.y; oa[2] += pv*v0.z; oa[3] += pv*v0.w;
          oa[4] += pv*v1.x; oa[5] += pv*v1.y; oa[6] += pv*v1.z; oa[7] += pv*v1.w;
          oa[8] += pv*v2.x; oa[9] += pv*v2.y; oa[10] += pv*v2.z; oa[11] += pv*v2.w;
          oa[12] += pv*v3.x; oa[13] += pv*v3.y; oa[14] += pv*v3.z; oa[15] += pv*v3.w;
        }
      }
#pragma unroll
      for (int e = 0; e < 16; ++e) {
#pragma unroll
        for (int d = 1; d < 16; d <<= 1) oa[e] += __shfl_xor(oa[e], d);
        oa[e] *= inv;
      }
      // out-projection: lane16 = channel c
      {
        const float* ow = a.cm_out_w + m * 256 + lane16 * 16;
        float acc = a.cm_out_b[m * 16 + lane16];
#pragma unroll
        for (int e = 0; e < 16; ++e) acc += oa[e] * ow[e];
        G[G_O + (m * NOFC + r) * 16 + lane16] = acc;
      }
    }
  }
  gbar(a.bar, 4);

  // ---- head (WG0 only) -------------------------------------------------
  if (wgid == 0) {
    for (int o = tid; o < 2 * NOFC; o += NT) {
      int half = o / NOFC, t = o - half * NOFC;
      const float* A = G + G_O + ((half ? 3 : 0) * NOFC + t) * 16;
      const float* B = G + G_O + ((half ? 2 : 1) * NOFC + t) * 16;
      float acc = 0.f;
#pragma unroll
      for (int c = 0; c < 16; ++c) acc += A[c] * B[c];
      S[DD + o] = sigmf(a.fc_w[half] * acc + a.fc_b[half]);
    }
    __syncthreads();
    for (int o = grp; o < NOFC; o += 64) {       // out1: 238-dot
      const float* wrow = a.out1_w + o * 238;
      float a0 = 0.f, a1 = 0.f;
#pragma unroll
      for (int t = 0; t < 14; ++t) {
        float wv = wrow[lane16 + 16 * t];
        float xv = S[DD + lane16 + 16 * t];
        if (t & 1) a1 += wv * xv; else a0 += wv * xv;
      }
      if (lane16 < 14) a0 += wrow[224 + lane16] * S[DD + 224 + lane16];
      float acc = a0 + a1;
#pragma unroll
      for (int m = 1; m < 16; m <<= 1) acc += __shfl_xor(acc, m);
      if (lane16 == 0) S[HH + o] = sigmf(acc + a.out1_b[o]);
    }
    __syncthreads();
    if (tid < 32) {
      int o2 = tid >> 4;
      const float* wrow = a.out2_w + o2 * NOFC;
      float a0 = 0.f;
#pragma unroll
      for (int t = 0; t < 8; ++t) {
        int idx = lane16 + 16 * t;
        if (idx < NOFC) a0 += wrow[idx] * S[HH + idx];
      }
      float acc = a0;
#pragma unroll
      for (int m = 1; m < 16; m <<= 1) acc += __shfl_xor(acc, m);
      if (lane16 == 0) a.out[o2] = sigmf(acc + a.out2_b[o2]);
    }
  }
}

extern "C" void kernel_launch(void* const* d_in, const int* in_sizes, int n_in,
                              void* d_out, int out_size, void* d_ws, size_t ws_size,
                              hipStream_t stream) {
  Args a;
  a.x        = (const float*)d_in[0];
  a.td_in_w  = (const float*)d_in[1];
  a.td_in_b  = (const float*)d_in[2];
  a.td_out_w = (const float*)d_in[3];
  a.td_out_b = (const float*)d_in[4];
  a.cm_in_w  = (const float*)d_in[5];
  a.cm_in_b  = (const float*)d_in[6];
  a.cm_out_w = (const float*)d_in[7];
  a.cm_out_b = (const float*)d_in[8];
  a.mc_w     = (const float*)d_in[9];
  a.mc_b     = (const float*)d_in[10];
  a.max_fc_w = (const float*)d_in[11];
  a.max_fc_b = (const float*)d_in[12];
  a.proj_w   = (const float*)d_in[13];
  a.ln_g     = (const float*)d_in[14];
  a.ln_b     = (const float*)d_in[15];
  a.fc_w     = (const float*)d_in[16];
  a.fc_b     = (const float*)d_in[17];
  a.out1_w   = (const float*)d_in[18];
  a.out1_b   = (const float*)d_in[19];
  a.out2_w   = (const float*)d_in[20];
  a.out2_b   = (const float*)d_in[21];
  a.out      = (float*)d_out;
  a.bar      = (unsigned int*)d_ws;
  a.G        = (float*)((char*)d_ws + 512);

  // zero the 5 barrier counters (64 B apart) every call — graph replays this.
  hipMemsetAsync(d_ws, 0, 512, stream);
  fused_cnn_kernel<<<dim3(NWG), dim3(NT), 0, stream>>>(a);
}